// Round 9
// baseline (356.286 us; speedup 1.0000x reference)
//
#include <hip/hip_runtime.h>
#include <math.h>

static constexpr int BB  = 4;
static constexpr int HH  = 1024;
static constexpr int WW  = 1024;
static constexpr int HWP = HH * WW;       // 1<<20
static constexpr int NPIX = BB * HWP;     // 4<<20
static constexpr int WPR = WW / 64;       // 16 words per image row
static constexpr int PW  = HWP / 64;      // 16384 words per image bitplane

// fused-stencil tile: 64 wide x 16 tall output (TY=16 -> ~28 KB LDS -> 5 blocks/CU)
static constexpr int TX = 64, TY = 16;
static constexpr int GH = 24,  GW = 72;   // gray   (pre-reflected halo)
static constexpr int HBH = 24, HBW = 68;  // hblur
static constexpr int VBH = 20, VBW = 68;  // vblur
static constexpr int MGH = 18, MGW = 66;  // mag

__device__ __forceinline__ int reflect_idx(int i, int n) {
    i = (i < 0) ? -i : i;                 // jnp.pad mode='reflect': -1 -> 1
    return (i >= n) ? (2 * n - 2 - i) : i;
}

// ---------- fused: gray -> hblur -> vblur -> sobel/mag -> dir -> NMS -> ballot ----------
__global__ void __launch_bounds__(256) k_front(const float* __restrict__ x,
                                               float* __restrict__ out0,
                                               unsigned long long* __restrict__ weakP,
                                               unsigned long long* __restrict__ strongP,
                                               double w0, double w1, double w2) {
    __shared__ double A[GH * GW];         // gray, then vblur
    __shared__ double B[HBH * HBW];       // hblur, then mag
    __shared__ unsigned char P[TY * TX];  // quantized direction, center pixels

    const int tid = threadIdx.x;
    const int x0  = blockIdx.x * TX;
    const int y0  = blockIdx.y * TY;
    const int b   = blockIdx.z;
    const float* base = x + (size_t)b * 3u * HWP;

    // S1: grayscale into A (rows/cols pre-reflected so later reads are raw)
    for (int idx = tid; idx < GH * GW; idx += 256) {
        int r = idx / GW, c = idx - r * GW;
        int gyr = reflect_idx(y0 + r - 4, HH);
        int gxr = reflect_idx(x0 + c - 4, WW);
        const float* rp = base + (size_t)gyr * WW;
        double rr = (double)rp[gxr];
        double gg = (double)rp[HWP + gxr];
        double bb = (double)rp[2 * HWP + gxr];
        A[idx] = rr * 0.299 + gg * 0.587 + bb * 0.114;
    }
    __syncthreads();

    // S2: hblur into B
    for (int idx = tid; idx < HBH * HBW; idx += 256) {
        int r = idx / HBW, c = idx - r * HBW;
        const double* g = &A[r * GW + c];
        double s;
        s  = w0 * g[0];
        s += w1 * g[1];
        s += w2 * g[2];
        s += w1 * g[3];
        s += w0 * g[4];
        B[idx] = s;
    }
    __syncthreads();

    // S3: vblur into A
    for (int idx = tid; idx < VBH * VBW; idx += 256) {
        int r = idx / VBW, c = idx - r * VBW;
        const double* h = &B[r * HBW + c];
        double s;
        s  = w0 * h[0];
        s += w1 * h[1 * HBW];
        s += w2 * h[2 * HBW];
        s += w1 * h[3 * HBW];
        s += w0 * h[4 * HBW];
        A[idx] = s;
    }
    __syncthreads();

    // S4: sobel magnitude into B (0 outside image = NMS zero pad) + dir bytes for center
    for (int idx = tid; idx < MGH * MGW; idx += 256) {
        int r = idx / MGW, c = idx - r * MGW;
        int gy = y0 + r - 1, gx = x0 + c - 1;
        double mg = 0.0;
        if (gy >= 0 && gy < HH && gx >= 0 && gx < WW) {
            int ym = gy > 0 ? gy - 1 : 0, yp = gy < HH - 1 ? gy + 1 : HH - 1;
            int xm = gx > 0 ? gx - 1 : 0, xp = gx < WW - 1 ? gx + 1 : WW - 1;
            auto BL = [&](int yy, int xx) -> double {
                return A[(yy - y0 + 2) * VBW + (xx - x0 + 2)];
            };
            double b00 = BL(ym, xm), b01 = BL(ym, gx), b02 = BL(ym, xp);
            double b10 = BL(gy, xm),                   b12 = BL(gy, xp);
            double b20 = BL(yp, xm), b21 = BL(yp, gx), b22 = BL(yp, xp);
            double gxv = -b00 + b02 - 2.0 * b10 + 2.0 * b12 - b20 + b22;
            double gyv = -b00 - 2.0 * b01 - b02 + b20 + 2.0 * b21 + b22;
            mg = sqrt(gxv * gxv + gyv * gyv + 1e-6);
            if (r >= 1 && r < TY + 1 && c >= 1 && c < TX + 1) {
                // octant classification == round(atan2(gy,gx)*4/pi) mod 8, boundary-exact
                double ax = fabs(gxv), ay = fabs(gyv);
                int p;
                if (ay < 0.41421356237309503 * ax)       // tan(22.5deg)
                    p = (gxv >= 0.0) ? 0 : 4;
                else if (ay < 2.4142135623730951 * ax)   // tan(67.5deg)
                    p = (gyv >= 0.0) ? ((gxv >= 0.0) ? 1 : 3)
                                     : ((gxv >= 0.0) ? 7 : 5);
                else
                    p = (gyv >= 0.0) ? 2 : 6;
                P[(r - 1) * TX + (c - 1)] = (unsigned char)p;
            }
        }
        B[r * MGW + c] = mg;
    }
    __syncthreads();

    // S5: NMS + thresholds + ballot (one wave = one 64px row-word)
    for (int k = 0; k < (TX * TY) / 256; ++k) {
        int idx = k * 256 + tid;
        int r = idx >> 6, c = idx & 63;
        double ctr = B[(r + 1) * MGW + (c + 1)];
        int p = P[idx];
        int dr = ((425   >> (2 * p)) & 3) - 1;
        int dc = ((36890 >> (2 * p)) & 3) - 1;
        double mp = B[(r + 1 + dr) * MGW + (c + 1 + dc)];
        double mn = B[(r + 1 - dr) * MGW + (c + 1 - dc)];
        bool ismax = ((ctr - mp) > 0.0) && ((ctr - mn) > 0.0);
        double sm = ismax ? ctr : 0.0;
        out0[(size_t)b * HWP + (size_t)(y0 + r) * WW + (x0 + c)] = (float)sm;
        bool strong = (sm > 0.2);
        bool weak   = (sm > 0.1) && !strong;
        unsigned long long wb = __ballot(weak);
        unsigned long long sb = __ballot(strong);
        if ((tid & 63) == 0) {
            int word = (y0 + r) * WPR + (x0 >> 6);
            weakP[(size_t)b * PW + word]   = wb;
            strongP[(size_t)b * PW + word] = sb;
        }
    }
}

// ---------------- hysteresis: single-launch worklist flood fill ----------------
__device__ __forceinline__ unsigned long long ks_fill(unsigned long long g, unsigned long long p) {
    unsigned long long q;
    q = p;        g |= q & (g << 1);
    q &= q << 1;  g |= q & (g << 2);
    q &= q << 2;  g |= q & (g << 4);
    q &= q << 4;  g |= q & (g << 8);
    q &= q << 8;  g |= q & (g << 16);
    q &= q << 16; g |= q & (g << 32);
    q = p;        g |= q & (g >> 1);
    q &= q >> 1;  g |= q & (g >> 2);
    q &= q >> 2;  g |= q & (g >> 4);
    q &= q >> 4;  g |= q & (g >> 8);
    q &= q >> 8;  g |= q & (g >> 16);
    q &= q >> 16; g |= q & (g >> 32);
    return g;
}

// one block per image; strips processed sequentially (Gauss-Seidel via global mem);
// dirty[] worklist, alternating sweep direction; exits at exact global fixed point.
__global__ void __launch_bounds__(256) k_hyst(const unsigned long long* __restrict__ weakP,
                                              unsigned long long* __restrict__ strongP) {
    __shared__ unsigned long long sp[HH + 2];   // spread-form strong rows of current strip
    __shared__ int s_changed;
    __shared__ int dirty[WPR];
    __shared__ int anyd;

    const int tid = threadIdx.x;
    const int b   = blockIdx.x;
    const unsigned long long* wp = weakP + (size_t)b * PW;
    unsigned long long* spl      = strongP + (size_t)b * PW;
    const int r0 = tid * 4;

    if (tid < WPR) dirty[tid] = 1;
    if (tid == 0) { sp[0] = 0; sp[HH + 1] = 0; s_changed = 0; }

    for (int fwd = 1; ; fwd ^= 1) {
        for (int k = 0; k < WPR; ++k) {
            const int tx = fwd ? k : (WPR - 1 - k);
            __syncthreads();                    // dirty writes visible; uniform read below
            if (!dirty[tx]) continue;
            __syncthreads();                    // all have read dirty[tx]
            if (tid == 0) dirty[tx] = 0;

            unsigned long long w[4], s[4], ho[4];
            for (int i = 0; i < 4; ++i) {
                int row = r0 + i, wi = row * WPR + tx;
                w[i] = wp[wi];
                s[i] = spl[wi];
                unsigned long long h = 0;       // halo from neighbor strips (current values)
                if (tx > 0)       h |= spl[wi - 1] >> 63;
                if (tx < WPR - 1) h |= spl[wi + 1] << 63;
                ho[i] = h;
                sp[row + 1] = (s[i] << 1) | s[i] | (s[i] >> 1) | h;
            }

            auto spread = [&](int i) -> unsigned long long {
                return (s[i] << 1) | s[i] | (s[i] >> 1) | ho[i];
            };

            int blockChanged = 0;
            for (;;) {
                __syncthreads();                // (A) sp writes + s_changed reset visible
                int ch = 0;
                unsigned long long up = sp[r0]; // down sweep (GS publish on change)
                for (int i = 0; i < 4; ++i) {
                    unsigned long long dn = (i < 3) ? spread(i + 1) : sp[r0 + 5];
                    unsigned long long g = s[i] | (w[i] & (up | spread(i) | dn));
                    g = ks_fill(g, w[i]);
                    if (g != s[i]) { s[i] = g; ch = 1; sp[r0 + i + 1] = spread(i); }
                    up = spread(i);
                }
                unsigned long long dn2 = sp[r0 + 5];  // up sweep
                for (int i = 3; i >= 0; --i) {
                    unsigned long long upv = (i > 0) ? spread(i - 1) : sp[r0];
                    unsigned long long g = s[i] | (w[i] & (upv | spread(i) | dn2));
                    g = ks_fill(g, w[i]);
                    if (g != s[i]) { s[i] = g; ch = 1; sp[r0 + i + 1] = spread(i); }
                    dn2 = spread(i);
                }
                if (ch) s_changed = 1;          // benign race: all writers store 1
                __syncthreads();                // (B) all sets done
                int live = s_changed;
                __syncthreads();                // (C) all reads done
                if (tid == 0) s_changed = 0;    // visible after next (A)
                if (!live) break;
                blockChanged = 1;
            }

            if (blockChanged) {                 // uniform across block
                for (int i = 0; i < 4; ++i) spl[(r0 + i) * WPR + tx] = s[i];
                if (tid == 0) {                 // mark neighbors for revisit
                    if (tx > 0)       dirty[tx - 1] = 1;
                    if (tx < WPR - 1) dirty[tx + 1] = 1;
                }
            }
        }
        __syncthreads();                        // all dirty updates visible
        if (tid == 0) {
            int a = 0;
            for (int i = 0; i < WPR; ++i) a |= dirty[i];
            anyd = a;
        }
        __syncthreads();
        if (!anyd) break;                       // exact global fixed point
    }
}

__global__ void k_edges(const unsigned long long* __restrict__ strongP, float* __restrict__ out1) {
    int i = blockIdx.x * blockDim.x + threadIdx.x;
    if (i >= NPIX) return;
    out1[i] = ((strongP[i >> 6] >> (i & 63)) & 1ull) ? 1.0f : 0.0f;
}

extern "C" void kernel_launch(void* const* d_in, const int* in_sizes, int n_in,
                              void* d_out, int out_size, void* d_ws, size_t ws_size,
                              hipStream_t stream) {
    const float* x = (const float*)d_in[0];
    float* out0 = (float*)d_out;          // suppressed magnitude [4,1,1024,1024]
    float* out1 = out0 + NPIX;            // edges [4,1,1024,1024]

    // workspace: weakP | strongP
    unsigned long long* weakP   = (unsigned long long*)d_ws;
    unsigned long long* strongP = weakP + (size_t)BB * PW;

    // gaussian weights, f64 ops mirroring the reference
    double g0 = exp(-2.0), g1 = exp(-0.5), g2 = 1.0;
    double sum = (((g0 + g1) + g2) + g1) + g0;
    double w0 = g0 / sum, w1 = g1 / sum, w2 = g2 / sum;

    k_front<<<dim3(WW / TX, HH / TY, BB), dim3(256), 0, stream>>>(
        x, out0, weakP, strongP, w0, w1, w2);

    k_hyst<<<dim3(BB), dim3(256), 0, stream>>>(weakP, strongP);

    k_edges<<<dim3(NPIX / 256), dim3(256), 0, stream>>>(strongP, out1);
}

// Round 10
// 181.098 us; speedup vs baseline: 1.9674x; 1.9674x over previous
//
#include <hip/hip_runtime.h>
#include <math.h>

static constexpr int BB  = 4;
static constexpr int HH  = 1024;
static constexpr int WW  = 1024;
static constexpr int HWP = HH * WW;       // 1<<20
static constexpr int NPIX = BB * HWP;     // 4<<20
static constexpr int WPR = WW / 64;       // 16 words per image row
static constexpr int PW  = HWP / 64;      // 16384 words per image bitplane
static constexpr int GRID_H = BB * WPR;   // 64 hysteresis blocks (all co-resident on 256 CUs)
static constexpr int MAXR = 96;           // round-flag array bound (convergence ~<=7 observed)

// fused-stencil tile: 64 wide x 16 tall output (TY=16 -> ~28 KB LDS -> 5 blocks/CU)
static constexpr int TX = 64, TY = 16;
static constexpr int GH = 24,  GW = 72;   // gray   (pre-reflected halo)
static constexpr int HBH = 24, HBW = 68;  // hblur
static constexpr int VBH = 20, VBW = 68;  // vblur
static constexpr int MGH = 18, MGW = 66;  // mag

__device__ __forceinline__ int reflect_idx(int i, int n) {
    i = (i < 0) ? -i : i;                 // jnp.pad mode='reflect': -1 -> 1
    return (i >= n) ? (2 * n - 2 - i) : i;
}

// ---------- fused: gray -> hblur -> vblur -> sobel/mag -> dir -> NMS -> ballot ----------
__global__ void __launch_bounds__(256) k_front(const float* __restrict__ x,
                                               float* __restrict__ out0,
                                               unsigned long long* __restrict__ weakP,
                                               unsigned long long* __restrict__ strongP,
                                               int* __restrict__ fc,
                                               double w0, double w1, double w2) {
    __shared__ double A[GH * GW];         // gray, then vblur
    __shared__ double B[HBH * HBW];       // hblur, then mag
    __shared__ unsigned char P[TY * TX];  // quantized direction, center pixels

    const int tid = threadIdx.x;
    const int x0  = blockIdx.x * TX;
    const int y0  = blockIdx.y * TY;
    const int b   = blockIdx.z;
    const float* base = x + (size_t)b * 3u * HWP;

    if (blockIdx.x == 0 && blockIdx.y == 0 && b == 0 && tid < 2 * MAXR)
        fc[tid] = 0;                      // zero flags[] and counts[] for k_hyst

    // S1: grayscale into A (rows/cols pre-reflected so later reads are raw)
    for (int idx = tid; idx < GH * GW; idx += 256) {
        int r = idx / GW, c = idx - r * GW;
        int gyr = reflect_idx(y0 + r - 4, HH);
        int gxr = reflect_idx(x0 + c - 4, WW);
        const float* rp = base + (size_t)gyr * WW;
        double rr = (double)rp[gxr];
        double gg = (double)rp[HWP + gxr];
        double bb = (double)rp[2 * HWP + gxr];
        A[idx] = rr * 0.299 + gg * 0.587 + bb * 0.114;
    }
    __syncthreads();

    // S2: hblur into B
    for (int idx = tid; idx < HBH * HBW; idx += 256) {
        int r = idx / HBW, c = idx - r * HBW;
        const double* g = &A[r * GW + c];
        double s;
        s  = w0 * g[0];
        s += w1 * g[1];
        s += w2 * g[2];
        s += w1 * g[3];
        s += w0 * g[4];
        B[idx] = s;
    }
    __syncthreads();

    // S3: vblur into A
    for (int idx = tid; idx < VBH * VBW; idx += 256) {
        int r = idx / VBW, c = idx - r * VBW;
        const double* h = &B[r * HBW + c];
        double s;
        s  = w0 * h[0];
        s += w1 * h[1 * HBW];
        s += w2 * h[2 * HBW];
        s += w1 * h[3 * HBW];
        s += w0 * h[4 * HBW];
        A[idx] = s;
    }
    __syncthreads();

    // S4: sobel magnitude into B (0 outside image = NMS zero pad) + dir bytes for center
    for (int idx = tid; idx < MGH * MGW; idx += 256) {
        int r = idx / MGW, c = idx - r * MGW;
        int gy = y0 + r - 1, gx = x0 + c - 1;
        double mg = 0.0;
        if (gy >= 0 && gy < HH && gx >= 0 && gx < WW) {
            int ym = gy > 0 ? gy - 1 : 0, yp = gy < HH - 1 ? gy + 1 : HH - 1;
            int xm = gx > 0 ? gx - 1 : 0, xp = gx < WW - 1 ? gx + 1 : WW - 1;
            auto BL = [&](int yy, int xx) -> double {
                return A[(yy - y0 + 2) * VBW + (xx - x0 + 2)];
            };
            double b00 = BL(ym, xm), b01 = BL(ym, gx), b02 = BL(ym, xp);
            double b10 = BL(gy, xm),                   b12 = BL(gy, xp);
            double b20 = BL(yp, xm), b21 = BL(yp, gx), b22 = BL(yp, xp);
            double gxv = -b00 + b02 - 2.0 * b10 + 2.0 * b12 - b20 + b22;
            double gyv = -b00 - 2.0 * b01 - b02 + b20 + 2.0 * b21 + b22;
            mg = sqrt(gxv * gxv + gyv * gyv + 1e-6);
            if (r >= 1 && r < TY + 1 && c >= 1 && c < TX + 1) {
                // octant classification == round(atan2(gy,gx)*4/pi) mod 8, boundary-exact
                double ax = fabs(gxv), ay = fabs(gyv);
                int p;
                if (ay < 0.41421356237309503 * ax)       // tan(22.5deg)
                    p = (gxv >= 0.0) ? 0 : 4;
                else if (ay < 2.4142135623730951 * ax)   // tan(67.5deg)
                    p = (gyv >= 0.0) ? ((gxv >= 0.0) ? 1 : 3)
                                     : ((gxv >= 0.0) ? 7 : 5);
                else
                    p = (gyv >= 0.0) ? 2 : 6;
                P[(r - 1) * TX + (c - 1)] = (unsigned char)p;
            }
        }
        B[r * MGW + c] = mg;
    }
    __syncthreads();

    // S5: NMS + thresholds + ballot (one wave = one 64px row-word)
    for (int k = 0; k < (TX * TY) / 256; ++k) {
        int idx = k * 256 + tid;
        int r = idx >> 6, c = idx & 63;
        double ctr = B[(r + 1) * MGW + (c + 1)];
        int p = P[idx];
        int dr = ((425   >> (2 * p)) & 3) - 1;
        int dc = ((36890 >> (2 * p)) & 3) - 1;
        double mp = B[(r + 1 + dr) * MGW + (c + 1 + dc)];
        double mn = B[(r + 1 - dr) * MGW + (c + 1 - dc)];
        bool ismax = ((ctr - mp) > 0.0) && ((ctr - mn) > 0.0);
        double sm = ismax ? ctr : 0.0;
        out0[(size_t)b * HWP + (size_t)(y0 + r) * WW + (x0 + c)] = (float)sm;
        bool strong = (sm > 0.2);
        bool weak   = (sm > 0.1) && !strong;
        unsigned long long wb = __ballot(weak);
        unsigned long long sb = __ballot(strong);
        if ((tid & 63) == 0) {
            int word = (y0 + r) * WPR + (x0 >> 6);
            weakP[(size_t)b * PW + word]   = wb;
            strongP[(size_t)b * PW + word] = sb;
        }
    }
}

// ---------------- hysteresis: single launch, 64 parallel strips, spin grid barrier ----------------
__device__ __forceinline__ unsigned long long ks_fill(unsigned long long g, unsigned long long p) {
    unsigned long long q;
    q = p;        g |= q & (g << 1);
    q &= q << 1;  g |= q & (g << 2);
    q &= q << 2;  g |= q & (g << 4);
    q &= q << 4;  g |= q & (g << 8);
    q &= q << 8;  g |= q & (g << 16);
    q &= q << 16; g |= q & (g << 32);
    q = p;        g |= q & (g >> 1);
    q &= q >> 1;  g |= q & (g >> 2);
    q &= q >> 2;  g |= q & (g >> 4);
    q &= q >> 4;  g |= q & (g >> 8);
    q &= q >> 8;  g |= q & (g >> 16);
    q &= q >> 16; g |= q & (g >> 32);
    return g;
}

__global__ void __launch_bounds__(256) k_hyst(const unsigned long long* __restrict__ weakP,
                                              unsigned long long* __restrict__ strongP,
                                              float* __restrict__ out1,
                                              int* __restrict__ fc) {
    __shared__ unsigned long long sp[HH + 2];   // spread-form strong rows (+zero halo)
    __shared__ int s_changed;
    __shared__ int s_live;

    int* flags  = fc;                           // [MAXR]
    int* counts = fc + MAXR;                    // [MAXR]

    const int tid = threadIdx.x;
    const int blk = blockIdx.x;                 // 64 blocks: b(2b) | tx(4b); strip 64w x 1024h
    const int b  = blk >> 4;
    const int tx = blk & 15;
    const unsigned long long* wp = weakP + (size_t)b * PW;
    unsigned long long* spl      = strongP + (size_t)b * PW;
    const int r0 = tid * 4;

    unsigned long long w[4], s[4], ho[4];
    for (int i = 0; i < 4; ++i) {
        int row = r0 + i, wi = row * WPR + tx;
        w[i] = wp[wi];                          // read-only plane: regular load
        s[i] = spl[wi];                         // own strip: exclusive ownership
        unsigned long long h = 0;               // halo from neighbor strips
        if (tx > 0)       h |= __hip_atomic_load(&spl[wi - 1], __ATOMIC_RELAXED,
                                                 __HIP_MEMORY_SCOPE_AGENT) >> 63;
        if (tx < WPR - 1) h |= __hip_atomic_load(&spl[wi + 1], __ATOMIC_RELAXED,
                                                 __HIP_MEMORY_SCOPE_AGENT) << 63;
        ho[i] = h;
        sp[row + 1] = (s[i] << 1) | s[i] | (s[i] >> 1) | h;
    }
    if (tid == 0) { sp[0] = 0; sp[HH + 1] = 0; s_changed = 0; }

    auto spread = [&](int i) -> unsigned long long {
        return (s[i] << 1) | s[i] | (s[i] >> 1) | ho[i];
    };

    for (int r = 0; r < MAXR; ++r) {
        // ---- local fixed point (GS within strip; publish sp[] immediately; monotone-safe)
        int blockChanged = 0;
        for (;;) {
            __syncthreads();                    // (A) sp writes + s_changed reset visible
            int ch = 0;
            unsigned long long up = sp[r0];     // down sweep
            for (int i = 0; i < 4; ++i) {
                unsigned long long dn = (i < 3) ? spread(i + 1) : sp[r0 + 5];
                unsigned long long g = s[i] | (w[i] & (up | spread(i) | dn));
                g = ks_fill(g, w[i]);
                if (g != s[i]) { s[i] = g; ch = 1; sp[r0 + i + 1] = spread(i); }
                up = spread(i);
            }
            unsigned long long dn2 = sp[r0 + 5];  // up sweep
            for (int i = 3; i >= 0; --i) {
                unsigned long long upv = (i > 0) ? spread(i - 1) : sp[r0];
                unsigned long long g = s[i] | (w[i] & (upv | spread(i) | dn2));
                g = ks_fill(g, w[i]);
                if (g != s[i]) { s[i] = g; ch = 1; sp[r0 + i + 1] = spread(i); }
                dn2 = spread(i);
            }
            if (ch) s_changed = 1;              // benign race: all writers store 1
            __syncthreads();                    // (B) all sets done
            int live = s_changed;
            __syncthreads();                    // (C) all reads done
            if (tid == 0) s_changed = 0;        // visible after next (A)
            if (!live) break;
            blockChanged = 1;
        }

        // ---- write back changed strip (coherent path) + round flag
        if (blockChanged) {                     // uniform across block
            for (int i = 0; i < 4; ++i)
                __hip_atomic_store(&spl[(r0 + i) * WPR + tx], s[i],
                                   __ATOMIC_RELAXED, __HIP_MEMORY_SCOPE_AGENT);
        }
        __syncthreads();                        // includes vmcnt(0): stores drained

        // ---- spin grid barrier; detect globally-quiet round
        if (tid == 0) {
            if (blockChanged)
                __hip_atomic_fetch_or(&flags[r], 1, __ATOMIC_RELEASE, __HIP_MEMORY_SCOPE_AGENT);
            __hip_atomic_fetch_add(&counts[r], 1, __ATOMIC_RELEASE, __HIP_MEMORY_SCOPE_AGENT);
            while (__hip_atomic_load(&counts[r], __ATOMIC_ACQUIRE,
                                     __HIP_MEMORY_SCOPE_AGENT) < GRID_H)
                __builtin_amdgcn_s_sleep(2);
            s_live = __hip_atomic_load(&flags[r], __ATOMIC_ACQUIRE, __HIP_MEMORY_SCOPE_AGENT);
        }
        __syncthreads();
        if (!s_live) break;                     // exact global fixed point

        // ---- reload halos (neighbors may have changed this round)
        for (int i = 0; i < 4; ++i) {
            int wi = (r0 + i) * WPR + tx;
            unsigned long long h = 0;
            if (tx > 0)       h |= __hip_atomic_load(&spl[wi - 1], __ATOMIC_RELAXED,
                                                     __HIP_MEMORY_SCOPE_AGENT) >> 63;
            if (tx < WPR - 1) h |= __hip_atomic_load(&spl[wi + 1], __ATOMIC_RELAXED,
                                                     __HIP_MEMORY_SCOPE_AGENT) << 63;
            ho[i] = h;
            sp[r0 + i + 1] = spread(i);
        }
    }

    // ---- epilogue: emit out1 for this strip (raw words via LDS, coalesced waves)
    for (int i = 0; i < 4; ++i) sp[r0 + i] = s[i];
    __syncthreads();
    float* ob = out1 + (size_t)b * HWP + (size_t)tx * 64;
    for (int i = tid; i < HH * 64; i += 256) {
        int row = i >> 6, lane = i & 63;
        ob[(size_t)row * WW + lane] = ((sp[row] >> lane) & 1ull) ? 1.0f : 0.0f;
    }
}

extern "C" void kernel_launch(void* const* d_in, const int* in_sizes, int n_in,
                              void* d_out, int out_size, void* d_ws, size_t ws_size,
                              hipStream_t stream) {
    const float* x = (const float*)d_in[0];
    float* out0 = (float*)d_out;          // suppressed magnitude [4,1,1024,1024]
    float* out1 = out0 + NPIX;            // edges [4,1,1024,1024]

    // workspace: weakP | strongP | fc (flags[MAXR] + counts[MAXR])
    unsigned long long* weakP   = (unsigned long long*)d_ws;
    unsigned long long* strongP = weakP + (size_t)BB * PW;
    int* fc = (int*)(strongP + (size_t)BB * PW);

    // gaussian weights, f64 ops mirroring the reference
    double g0 = exp(-2.0), g1 = exp(-0.5), g2 = 1.0;
    double sum = (((g0 + g1) + g2) + g1) + g0;
    double w0 = g0 / sum, w1 = g1 / sum, w2 = g2 / sum;

    k_front<<<dim3(WW / TX, HH / TY, BB), dim3(256), 0, stream>>>(
        x, out0, weakP, strongP, fc, w0, w1, w2);

    k_hyst<<<dim3(GRID_H), dim3(256), 0, stream>>>(weakP, strongP, out1, fc);
}

// Round 11
// 163.444 us; speedup vs baseline: 2.1799x; 1.1080x over previous
//
#include <hip/hip_runtime.h>
#include <math.h>

static constexpr int BB  = 4;
static constexpr int HH  = 1024;
static constexpr int WW  = 1024;
static constexpr int HWP = HH * WW;       // 1<<20
static constexpr int NPIX = BB * HWP;     // 4<<20
static constexpr int WPR = WW / 64;       // 16 words per image row
static constexpr int PW  = HWP / 64;      // 16384 words per image bitplane
static constexpr int ROUNDS = 10;
static constexpr int NT  = BB * 16 * 16;  // 1024 hysteresis tiles (64x64 px, one wave each)
static constexpr int RF  = ROUNDS + 1;    // flags array length
static constexpr int FCN = RF + RF * NT;  // flags[RF] + dirt[RF][NT]

// fused-stencil tile: 64 wide x 16 tall output (TY=16 -> ~28 KB LDS -> 5 blocks/CU)
static constexpr int TX = 64, TY = 16;
static constexpr int GH = 24,  GW = 72;   // gray   (pre-reflected halo)
static constexpr int HBH = 24, HBW = 68;  // hblur
static constexpr int VBH = 20, VBW = 68;  // vblur
static constexpr int MGH = 18, MGW = 66;  // mag

__device__ __forceinline__ int reflect_idx(int i, int n) {
    i = (i < 0) ? -i : i;                 // jnp.pad mode='reflect': -1 -> 1
    return (i >= n) ? (2 * n - 2 - i) : i;
}

// ---------- fused: gray -> hblur -> vblur -> sobel/mag -> dir -> NMS -> ballot ----------
__global__ void __launch_bounds__(256) k_front(const float* __restrict__ x,
                                               float* __restrict__ out0,
                                               unsigned long long* __restrict__ weakP,
                                               unsigned long long* __restrict__ strongP,
                                               int* __restrict__ fc,
                                               double w0, double w1, double w2) {
    __shared__ double A[GH * GW];         // gray, then vblur
    __shared__ double B[HBH * HBW];       // hblur, then mag
    __shared__ unsigned char P[TY * TX];  // quantized direction, center pixels

    const int tid = threadIdx.x;
    const int x0  = blockIdx.x * TX;
    const int y0  = blockIdx.y * TY;
    const int b   = blockIdx.z;
    const float* base = x + (size_t)b * 3u * HWP;

    if (blockIdx.x == 0 && blockIdx.y == 0 && b == 0) {
        // flags[0]=1, dirt[0][*]=1, rest 0
        for (int i = tid; i < FCN; i += 256)
            fc[i] = (i == 0 || (i >= RF && i < RF + NT)) ? 1 : 0;
    }

    // S1: grayscale into A (rows/cols pre-reflected so later reads are raw)
    for (int idx = tid; idx < GH * GW; idx += 256) {
        int r = idx / GW, c = idx - r * GW;
        int gyr = reflect_idx(y0 + r - 4, HH);
        int gxr = reflect_idx(x0 + c - 4, WW);
        const float* rp = base + (size_t)gyr * WW;
        double rr = (double)rp[gxr];
        double gg = (double)rp[HWP + gxr];
        double bb = (double)rp[2 * HWP + gxr];
        A[idx] = rr * 0.299 + gg * 0.587 + bb * 0.114;
    }
    __syncthreads();

    // S2: hblur into B
    for (int idx = tid; idx < HBH * HBW; idx += 256) {
        int r = idx / HBW, c = idx - r * HBW;
        const double* g = &A[r * GW + c];
        double s;
        s  = w0 * g[0];
        s += w1 * g[1];
        s += w2 * g[2];
        s += w1 * g[3];
        s += w0 * g[4];
        B[idx] = s;
    }
    __syncthreads();

    // S3: vblur into A
    for (int idx = tid; idx < VBH * VBW; idx += 256) {
        int r = idx / VBW, c = idx - r * VBW;
        const double* h = &B[r * HBW + c];
        double s;
        s  = w0 * h[0];
        s += w1 * h[1 * HBW];
        s += w2 * h[2 * HBW];
        s += w1 * h[3 * HBW];
        s += w0 * h[4 * HBW];
        A[idx] = s;
    }
    __syncthreads();

    // S4: sobel magnitude into B (0 outside image = NMS zero pad) + dir bytes for center
    for (int idx = tid; idx < MGH * MGW; idx += 256) {
        int r = idx / MGW, c = idx - r * MGW;
        int gy = y0 + r - 1, gx = x0 + c - 1;
        double mg = 0.0;
        if (gy >= 0 && gy < HH && gx >= 0 && gx < WW) {
            int ym = gy > 0 ? gy - 1 : 0, yp = gy < HH - 1 ? gy + 1 : HH - 1;
            int xm = gx > 0 ? gx - 1 : 0, xp = gx < WW - 1 ? gx + 1 : WW - 1;
            auto BL = [&](int yy, int xx) -> double {
                return A[(yy - y0 + 2) * VBW + (xx - x0 + 2)];
            };
            double b00 = BL(ym, xm), b01 = BL(ym, gx), b02 = BL(ym, xp);
            double b10 = BL(gy, xm),                   b12 = BL(gy, xp);
            double b20 = BL(yp, xm), b21 = BL(yp, gx), b22 = BL(yp, xp);
            double gxv = -b00 + b02 - 2.0 * b10 + 2.0 * b12 - b20 + b22;
            double gyv = -b00 - 2.0 * b01 - b02 + b20 + 2.0 * b21 + b22;
            mg = sqrt(gxv * gxv + gyv * gyv + 1e-6);
            if (r >= 1 && r < TY + 1 && c >= 1 && c < TX + 1) {
                // octant classification == round(atan2(gy,gx)*4/pi) mod 8, boundary-exact
                double ax = fabs(gxv), ay = fabs(gyv);
                int p;
                if (ay < 0.41421356237309503 * ax)       // tan(22.5deg)
                    p = (gxv >= 0.0) ? 0 : 4;
                else if (ay < 2.4142135623730951 * ax)   // tan(67.5deg)
                    p = (gyv >= 0.0) ? ((gxv >= 0.0) ? 1 : 3)
                                     : ((gxv >= 0.0) ? 7 : 5);
                else
                    p = (gyv >= 0.0) ? 2 : 6;
                P[(r - 1) * TX + (c - 1)] = (unsigned char)p;
            }
        }
        B[r * MGW + c] = mg;
    }
    __syncthreads();

    // S5: NMS + thresholds + ballot (one wave = one 64px row-word)
    for (int k = 0; k < (TX * TY) / 256; ++k) {
        int idx = k * 256 + tid;
        int r = idx >> 6, c = idx & 63;
        double ctr = B[(r + 1) * MGW + (c + 1)];
        int p = P[idx];
        int dr = ((425   >> (2 * p)) & 3) - 1;
        int dc = ((36890 >> (2 * p)) & 3) - 1;
        double mp = B[(r + 1 + dr) * MGW + (c + 1 + dc)];
        double mn = B[(r + 1 - dr) * MGW + (c + 1 - dc)];
        bool ismax = ((ctr - mp) > 0.0) && ((ctr - mn) > 0.0);
        double sm = ismax ? ctr : 0.0;
        out0[(size_t)b * HWP + (size_t)(y0 + r) * WW + (x0 + c)] = (float)sm;
        bool strong = (sm > 0.2);
        bool weak   = (sm > 0.1) && !strong;
        unsigned long long wb = __ballot(weak);
        unsigned long long sb = __ballot(strong);
        if ((tid & 63) == 0) {
            int word = (y0 + r) * WPR + (x0 >> 6);
            weakP[(size_t)b * PW + word]   = wb;
            strongP[(size_t)b * PW + word] = sb;
        }
    }
}

// ---------------- hysteresis: wave-per-64x64-tile flood fill, dirty worklist ----------------
__device__ __forceinline__ unsigned long long ks_fill(unsigned long long g, unsigned long long p) {
    unsigned long long q;
    q = p;        g |= q & (g << 1);
    q &= q << 1;  g |= q & (g << 2);
    q &= q << 2;  g |= q & (g << 4);
    q &= q << 4;  g |= q & (g << 8);
    q &= q << 8;  g |= q & (g << 16);
    q &= q << 16; g |= q & (g << 32);
    q = p;        g |= q & (g >> 1);
    q &= q >> 1;  g |= q & (g >> 2);
    q &= q >> 2;  g |= q & (g >> 4);
    q &= q >> 4;  g |= q & (g >> 8);
    q &= q >> 8;  g |= q & (g >> 16);
    q &= q >> 16; g |= q & (g >> 32);
    return g;
}

// 256 blocks x 256 threads = 1024 waves; wave = one 64x64 tile; no __syncthreads anywhere.
__global__ void __launch_bounds__(256) k_pass(const unsigned long long* __restrict__ weakP,
                                              unsigned long long* __restrict__ strongP,
                                              int* __restrict__ flags,
                                              int* __restrict__ dirt, int rr) {
    if (flags[rr - 1] == 0) return;           // previous round globally quiet

    const int lane = threadIdx.x & 63;
    const int wid  = (blockIdx.x << 2) | (threadIdx.x >> 6);   // tile id 0..1023
    const int b  = wid >> 8;                  // b(2b) | ty(4b) | tx(4b)
    const int ty = (wid >> 4) & 15;
    const int tx = wid & 15;
    const int tb = b << 8;

    // re-run only if an 8-neighbor tile changed last round (self at FP if halos unchanged)
    const int* d0 = dirt + (size_t)(rr - 1) * NT;
    int go = 0;
    if (ty > 0)  { go |= d0[tb + ((ty - 1) << 4) + tx];
                   if (tx > 0)  go |= d0[tb + ((ty - 1) << 4) + tx - 1];
                   if (tx < 15) go |= d0[tb + ((ty - 1) << 4) + tx + 1]; }
    if (ty < 15) { go |= d0[tb + ((ty + 1) << 4) + tx];
                   if (tx > 0)  go |= d0[tb + ((ty + 1) << 4) + tx - 1];
                   if (tx < 15) go |= d0[tb + ((ty + 1) << 4) + tx + 1]; }
    if (tx > 0)  go |= d0[tb + (ty << 4) + tx - 1];
    if (tx < 15) go |= d0[tb + (ty << 4) + tx + 1];
    if (!go) return;                          // wave-uniform

    const unsigned long long* wp = weakP + (size_t)b * PW;
    unsigned long long* spl      = strongP + (size_t)b * PW;
    const int row = (ty << 6) + lane;
    const int wi  = row * WPR + tx;
    unsigned long long w = wp[wi];
    unsigned long long s = spl[wi];
    unsigned long long ho = 0;                // static left/right halo bits (Jacobi across tiles)
    if (tx > 0)  ho |= spl[wi - 1] >> 63;
    if (tx < 15) ho |= spl[wi + 1] << 63;
    unsigned long long top = 0, bot = 0;      // static top/bottom halo rows (spread form)
    if (lane == 0 && ty > 0) {
        int hw = (row - 1) * WPR + tx;
        unsigned long long hs = spl[hw];
        top = (hs << 1) | hs | (hs >> 1);
        if (tx > 0)  top |= spl[hw - 1] >> 63;
        if (tx < 15) top |= spl[hw + 1] << 63;
    }
    if (lane == 63 && ty < 15) {
        int hw = (row + 1) * WPR + tx;
        unsigned long long hs = spl[hw];
        bot = (hs << 1) | hs | (hs >> 1);
        if (tx > 0)  bot |= spl[hw - 1] >> 63;
        if (tx < 15) bot |= spl[hw + 1] << 63;
    }

    // wave-local fixed point: shuffles for vertical, ks_fill for horizontal, ballot to stop
    int changed = 0;
    for (;;) {
        unsigned long long sp = (s << 1) | s | (s >> 1) | ho;
        unsigned long long up = __shfl_up(sp, 1);
        unsigned long long dn = __shfl_down(sp, 1);
        if (lane == 0)  up = top;
        if (lane == 63) dn = bot;
        unsigned long long g = s | (w & (up | sp | dn));
        g = ks_fill(g, w);
        int ch = (g != s);
        s = g;
        if (!__any(ch)) break;
        changed = 1;                          // uniform: set by all lanes together
    }

    if (changed) {
        spl[wi] = s;                          // kernel boundary republishes for next round
        if (lane == 0) {
            dirt[(size_t)rr * NT + tb + (ty << 4) + tx] = 1;
            atomicOr(&flags[rr], 1);
        }
    }
}

__global__ void k_edges(const unsigned long long* __restrict__ strongP, float* __restrict__ out1) {
    int i = blockIdx.x * blockDim.x + threadIdx.x;
    if (i >= NPIX) return;
    out1[i] = ((strongP[i >> 6] >> (i & 63)) & 1ull) ? 1.0f : 0.0f;
}

extern "C" void kernel_launch(void* const* d_in, const int* in_sizes, int n_in,
                              void* d_out, int out_size, void* d_ws, size_t ws_size,
                              hipStream_t stream) {
    const float* x = (const float*)d_in[0];
    float* out0 = (float*)d_out;          // suppressed magnitude [4,1,1024,1024]
    float* out1 = out0 + NPIX;            // edges [4,1,1024,1024]

    // workspace: weakP | strongP | fc (flags[RF] + dirt[RF][NT])
    unsigned long long* weakP   = (unsigned long long*)d_ws;
    unsigned long long* strongP = weakP + (size_t)BB * PW;
    int* fc    = (int*)(strongP + (size_t)BB * PW);
    int* flags = fc;
    int* dirt  = fc + RF;

    // gaussian weights, f64 ops mirroring the reference
    double g0 = exp(-2.0), g1 = exp(-0.5), g2 = 1.0;
    double sum = (((g0 + g1) + g2) + g1) + g0;
    double w0 = g0 / sum, w1 = g1 / sum, w2 = g2 / sum;

    k_front<<<dim3(WW / TX, HH / TY, BB), dim3(256), 0, stream>>>(
        x, out0, weakP, strongP, fc, w0, w1, w2);

    for (int r = 1; r <= ROUNDS; ++r)
        k_pass<<<dim3(256), dim3(256), 0, stream>>>(weakP, strongP, flags, dirt, r);

    k_edges<<<dim3(NPIX / 256), dim3(256), 0, stream>>>(strongP, out1);
}